// Round 1
// baseline (296.008 us; speedup 1.0000x reference)
//
#include <hip/hip_runtime.h>
#include <hip/hip_bf16.h>

#define B_ 4
#define N_ 1024
#define M_ 32
#define C_ 128
#define D_ 64
#define BM_ (B_*M_)   // 128 independent attention problems

typedef float f32x4 __attribute__((ext_vector_type(4)));
typedef short short8 __attribute__((ext_vector_type(8)));

// ---------------------------------------------------------------------------
// Kernel 0: transpose weights to bf16, concatenated [256 cols][128 k].
// cols 0-63 = w_q (scaled by 1/sqrt(64)=0.125), 64-127 = w_k, 128-255 = w_v.
// ---------------------------------------------------------------------------
__global__ __launch_bounds__(256) void prep_weights(
    const float* __restrict__ wq, const float* __restrict__ wk,
    const float* __restrict__ wv, __hip_bfloat16* __restrict__ wt) {
  int idx = blockIdx.x * 256 + threadIdx.x;   // 0 .. 32767
  int col = idx >> 7;      // 0..255
  int kk  = idx & 127;     // 0..127
  float v;
  if (col < 64)        v = wq[kk * 64 + col] * 0.125f;
  else if (col < 128)  v = wk[kk * 64 + (col - 64)];
  else                 v = wv[kk * 128 + (col - 128)];
  wt[col * 128 + kk] = __float2bfloat16(v);
}

// ---------------------------------------------------------------------------
// Kernel 1: LayerNorm (over C) + Q/K/V projections via MFMA.
// Grid: 128 (b,m) * 16 row-tiles of 64. Block: 256 threads (4 waves).
// Q,K stored [bm][N][64] bf16; V stored transposed [bm][C][N] bf16.
// ---------------------------------------------------------------------------
__global__ __launch_bounds__(256) void ln_qkv(
    const float* __restrict__ x, const float* __restrict__ gamma,
    const float* __restrict__ beta, const __hip_bfloat16* __restrict__ wt,
    __hip_bfloat16* __restrict__ q, __hip_bfloat16* __restrict__ k,
    __hip_bfloat16* __restrict__ vt) {
  __shared__ float xs[64][128];                       // 32 KB
  __shared__ alignas(16) __hip_bfloat16 xn[64][136];  // +8 pad (16B multiple)

  int bid = blockIdx.x;
  int bm  = bid >> 4;
  int n0  = (bid & 15) * 64;
  int b   = bm >> 5, m = bm & 31;
  int tid = threadIdx.x;

  // stage x rows [n0, n0+64) for fixed (b,m): coalesced float4
  const float* xbase = x + ((((size_t)b * N_ + n0) * M_ + m) * C_);
  #pragma unroll
  for (int it = 0; it < 8; ++it) {
    int f4 = it * 256 + tid;        // 0..2047 float4 units
    int r = f4 >> 5, c4 = f4 & 31;
    float4 v = *reinterpret_cast<const float4*>(xbase + (size_t)r * (M_ * C_) + c4 * 4);
    *reinterpret_cast<float4*>(&xs[r][c4 * 4]) = v;
  }
  __syncthreads();

  // LayerNorm: 4 threads per row (same wave), shfl-combine partial sums
  {
    int r = tid >> 2, sub = tid & 3;
    float s = 0.f, sq = 0.f;
    #pragma unroll
    for (int i = 0; i < 32; ++i) {
      float v = xs[r][sub * 32 + i];
      s += v; sq += v * v;
    }
    s  += __shfl_xor(s, 1);  s  += __shfl_xor(s, 2);
    sq += __shfl_xor(sq, 1); sq += __shfl_xor(sq, 2);
    float mean = s * (1.f / 128.f);
    float var  = sq * (1.f / 128.f) - mean * mean;
    float rstd = rsqrtf(var + 1e-3f);
    #pragma unroll
    for (int i = 0; i < 32; ++i) {
      int c = sub * 32 + i;
      float v = (xs[r][c] - mean) * rstd * gamma[c] + beta[c];
      xn[r][c] = __float2bfloat16(v);
    }
  }
  __syncthreads();

  // MFMA projections: wave w owns rows [w*16, w*16+16), all 256 output cols
  int w = tid >> 6, lane = tid & 63, lr = lane & 15, lh = lane >> 4;

  short8 a[4];
  #pragma unroll
  for (int h = 0; h < 4; ++h)
    a[h] = *reinterpret_cast<const short8*>(&xn[w * 16 + lr][h * 32 + lh * 8]);

  const f32x4 fzero = {0.f, 0.f, 0.f, 0.f};
  #pragma unroll
  for (int ct = 0; ct < 16; ++ct) {
    f32x4 acc = fzero;
    #pragma unroll
    for (int h = 0; h < 4; ++h) {
      short8 bf = *reinterpret_cast<const short8*>(
          &wt[(ct * 16 + lr) * 128 + h * 32 + lh * 8]);
      acc = __builtin_amdgcn_mfma_f32_16x16x32_bf16(a[h], bf, acc, 0, 0, 0);
    }
    int col = ct * 16 + lr;             // D-layout: col = lane&15
    int nb  = n0 + w * 16 + lh * 4;     // D-layout: row = (lane>>4)*4 + r
    #pragma unroll
    for (int r = 0; r < 4; ++r) {
      int n = nb + r;
      __hip_bfloat16 val = __float2bfloat16(acc[r]);
      if (col < 64)
        q[((size_t)bm * N_ + n) * D_ + col] = val;
      else if (col < 128)
        k[((size_t)bm * N_ + n) * D_ + (col - 64)] = val;
      else
        vt[((size_t)bm * C_ + (col - 128)) * N_ + n] = val;
    }
  }
}

// ---------------------------------------------------------------------------
// Kernel 2: flash attention per (b,m). Grid: 128 * 16 Q-tiles of 64 rows.
// Block 256 threads = 4 waves, each wave owns 16 Q rows. KV tiles of 32.
// Epilogue: out = x + (O / l) * lam, written in [B,N,M,C] layout.
// ---------------------------------------------------------------------------
__global__ __launch_bounds__(256) void attn_kernel(
    const float* __restrict__ x, const float* __restrict__ lam,
    const __hip_bfloat16* __restrict__ q, const __hip_bfloat16* __restrict__ k,
    const __hip_bfloat16* __restrict__ vt, float* __restrict__ out) {
  __shared__ alignas(16) __hip_bfloat16 kt[32][72];     // K tile, +8 pad
  __shared__ alignas(16) __hip_bfloat16 vtt[128][40];   // V^T tile, +8 pad
  __shared__ alignas(16) __hip_bfloat16 pt[4][16][40];  // per-wave P tile

  int bid = blockIdx.x;
  int bm  = bid >> 4;
  int n0  = (bid & 15) * 64;
  int b   = bm >> 5, m = bm & 31;
  int tid = threadIdx.x;
  int w = tid >> 6, lane = tid & 63, lr = lane & 15, lh = lane >> 4;

  // Q fragments for this wave's 16 rows (scores scale folded into w_q)
  short8 qf[2];
  {
    int qrow = n0 + w * 16 + lr;
    const __hip_bfloat16* qp = q + ((size_t)bm * N_ + qrow) * D_;
    qf[0] = *reinterpret_cast<const short8*>(qp + lh * 8);
    qf[1] = *reinterpret_cast<const short8*>(qp + 32 + lh * 8);
  }

  float m_run[4], l_run[4];
  f32x4 acc[8];
  const f32x4 fzero = {0.f, 0.f, 0.f, 0.f};
  #pragma unroll
  for (int r = 0; r < 4; ++r) { m_run[r] = -1e30f; l_run[r] = 0.f; }
  #pragma unroll
  for (int ct = 0; ct < 8; ++ct) acc[ct] = fzero;

  for (int t = 0; t < 32; ++t) {
    int j0 = t * 32;
    // stage K tile: 32 rows x 64 bf16 (each thread one 16B chunk)
    {
      int row = tid >> 3, c8 = tid & 7;
      short8 v = *reinterpret_cast<const short8*>(
          &k[((size_t)bm * N_ + j0 + row) * D_ + c8 * 8]);
      *reinterpret_cast<short8*>(&kt[row][c8 * 8]) = v;
    }
    // stage V^T tile: 128 rows x 32 bf16 (each thread 32B)
    {
      int row = tid >> 1, half = tid & 1;
      const __hip_bfloat16* vp = &vt[((size_t)bm * C_ + row) * N_ + j0 + half * 16];
      short8 v0 = *reinterpret_cast<const short8*>(vp);
      short8 v1 = *reinterpret_cast<const short8*>(vp + 8);
      *reinterpret_cast<short8*>(&vtt[row][half * 16]) = v0;
      *reinterpret_cast<short8*>(&vtt[row][half * 16 + 8]) = v1;
    }
    __syncthreads();

    // scores S[16 q][32 j] as two 16x16 MFMA tiles (K-dim 64 = 2 chunks)
    f32x4 s[2];
    #pragma unroll
    for (int jt = 0; jt < 2; ++jt) {
      s[jt] = fzero;
      #pragma unroll
      for (int h = 0; h < 2; ++h) {
        short8 kf = *reinterpret_cast<const short8*>(
            &kt[jt * 16 + lr][h * 32 + lh * 8]);
        s[jt] = __builtin_amdgcn_mfma_f32_16x16x32_bf16(qf[h], kf, s[jt], 0, 0, 0);
      }
    }

    // online softmax (row r of lane group lh -> q row lh*4+r)
    float ps[2][4];
    #pragma unroll
    for (int r = 0; r < 4; ++r) {
      float mt = fmaxf(s[0][r], s[1][r]);
      mt = fmaxf(mt, __shfl_xor(mt, 1));
      mt = fmaxf(mt, __shfl_xor(mt, 2));
      mt = fmaxf(mt, __shfl_xor(mt, 4));
      mt = fmaxf(mt, __shfl_xor(mt, 8));
      float mnew = fmaxf(m_run[r], mt);
      float fac  = __expf(m_run[r] - mnew);
      float p0 = __expf(s[0][r] - mnew);
      float p1 = __expf(s[1][r] - mnew);
      ps[0][r] = p0; ps[1][r] = p1;
      float rs = p0 + p1;
      rs += __shfl_xor(rs, 1); rs += __shfl_xor(rs, 2);
      rs += __shfl_xor(rs, 4); rs += __shfl_xor(rs, 8);
      l_run[r] = l_run[r] * fac + rs;
      m_run[r] = mnew;
      #pragma unroll
      for (int ct = 0; ct < 8; ++ct) acc[ct][r] *= fac;
    }

    // P (D-layout) -> LDS -> A-fragment layout (per-wave buffer, no barrier)
    #pragma unroll
    for (int jt = 0; jt < 2; ++jt)
      #pragma unroll
      for (int r = 0; r < 4; ++r)
        pt[w][lh * 4 + r][jt * 16 + lr] = __float2bfloat16(ps[jt][r]);
    short8 pf = *reinterpret_cast<const short8*>(&pt[w][lr][lh * 8]);

    // O += P @ V : 8 column tiles of 16
    #pragma unroll
    for (int ct = 0; ct < 8; ++ct) {
      short8 vf = *reinterpret_cast<const short8*>(&vtt[ct * 16 + lr][lh * 8]);
      acc[ct] = __builtin_amdgcn_mfma_f32_16x16x32_bf16(pf, vf, acc[ct], 0, 0, 0);
    }
    __syncthreads();
  }

  // epilogue: normalize, residual add, scale by lam; output [B,N,M,C]
  float rinv[4];
  #pragma unroll
  for (int r = 0; r < 4; ++r) rinv[r] = 1.f / l_run[r];
  #pragma unroll
  for (int ct = 0; ct < 8; ++ct) {
    int c = ct * 16 + lr;
    float lamc = lam[c];
    #pragma unroll
    for (int r = 0; r < 4; ++r) {
      int n = n0 + w * 16 + lh * 4 + r;
      size_t idx = ((((size_t)b * N_ + n) * M_ + m) * C_) + c;
      out[idx] = x[idx] + acc[ct][r] * rinv[r] * lamc;
    }
  }
}

// ---------------------------------------------------------------------------
extern "C" void kernel_launch(void* const* d_in, const int* in_sizes, int n_in,
                              void* d_out, int out_size, void* d_ws, size_t ws_size,
                              hipStream_t stream) {
  const float* x     = (const float*)d_in[0];
  const float* gamma = (const float*)d_in[1];
  const float* beta  = (const float*)d_in[2];
  const float* wq    = (const float*)d_in[3];
  const float* wk    = (const float*)d_in[4];
  const float* wv    = (const float*)d_in[5];
  const float* lam   = (const float*)d_in[6];
  float* out = (float*)d_out;

  __hip_bfloat16* ws = (__hip_bfloat16*)d_ws;
  __hip_bfloat16* wt = ws;                       // 256*128
  __hip_bfloat16* q  = wt + 256 * 128;           // 128*1024*64
  __hip_bfloat16* k  = q + (size_t)BM_ * N_ * D_; // 128*1024*64
  __hip_bfloat16* vt = k + (size_t)BM_ * N_ * D_; // 128*128*1024 (transposed)

  prep_weights<<<128, 256, 0, stream>>>(wq, wk, wv, wt);
  ln_qkv<<<BM_ * (N_ / 64), 256, 0, stream>>>(x, gamma, beta, wt, q, k, vt);
  attn_kernel<<<BM_ * (N_ / 64), 256, 0, stream>>>(x, lam, q, k, vt, out);
}

// Round 2
// 218.488 us; speedup vs baseline: 1.3548x; 1.3548x over previous
//
#include <hip/hip_runtime.h>
#include <hip/hip_bf16.h>

#define B_ 4
#define N_ 1024
#define M_ 32
#define C_ 128
#define D_ 64
#define BM_ (B_*M_)   // 128 independent attention problems

typedef float f32x4 __attribute__((ext_vector_type(4)));
typedef float f32x16 __attribute__((ext_vector_type(16)));
typedef short short8 __attribute__((ext_vector_type(8)));
typedef short short4v __attribute__((ext_vector_type(4)));

#define EXP2(x) __builtin_amdgcn_exp2f(x)

// ---------------------------------------------------------------------------
// Kernel 0: transpose weights to bf16, concatenated [256 cols][128 k].
// cols 0-63 = w_q scaled by (1/sqrt(64))*log2(e)  (exp2-domain softmax),
// 64-127 = w_k, 128-255 = w_v.
// ---------------------------------------------------------------------------
__global__ __launch_bounds__(256) void prep_weights(
    const float* __restrict__ wq, const float* __restrict__ wk,
    const float* __restrict__ wv, __hip_bfloat16* __restrict__ wt) {
  int idx = blockIdx.x * 256 + threadIdx.x;   // 0 .. 32767
  int col = idx >> 7;      // 0..255
  int kk  = idx & 127;     // 0..127
  float v;
  if (col < 64)        v = wq[kk * 64 + col] * (0.125f * 1.44269504088896f);
  else if (col < 128)  v = wk[kk * 64 + (col - 64)];
  else                 v = wv[kk * 128 + (col - 128)];
  wt[col * 128 + kk] = __float2bfloat16(v);
}

// ---------------------------------------------------------------------------
// Kernel 1: LayerNorm (over C) + Q/K/V projections via MFMA.
// Grid: 128 (b,m) * 16 row-tiles of 64. Block: 256 threads (4 waves).
// Q,K stored [bm][N][64] bf16; V stored transposed [bm][C][N] bf16.
// ---------------------------------------------------------------------------
__global__ __launch_bounds__(256) void ln_qkv(
    const float* __restrict__ x, const float* __restrict__ gamma,
    const float* __restrict__ beta, const __hip_bfloat16* __restrict__ wt,
    __hip_bfloat16* __restrict__ q, __hip_bfloat16* __restrict__ k,
    __hip_bfloat16* __restrict__ vt) {
  __shared__ float xs[64][128];                       // 32 KB
  __shared__ alignas(16) __hip_bfloat16 xn[64][136];  // +8 pad (16B multiple)

  int bid = blockIdx.x;
  int bm  = bid >> 4;
  int n0  = (bid & 15) * 64;
  int b   = bm >> 5, m = bm & 31;
  int tid = threadIdx.x;

  // stage x rows [n0, n0+64) for fixed (b,m): coalesced float4
  const float* xbase = x + ((((size_t)b * N_ + n0) * M_ + m) * C_);
  #pragma unroll
  for (int it = 0; it < 8; ++it) {
    int f4 = it * 256 + tid;        // 0..2047 float4 units
    int r = f4 >> 5, c4 = f4 & 31;
    float4 v = *reinterpret_cast<const float4*>(xbase + (size_t)r * (M_ * C_) + c4 * 4);
    *reinterpret_cast<float4*>(&xs[r][c4 * 4]) = v;
  }
  __syncthreads();

  // LayerNorm: 4 threads per row (same wave), shfl-combine partial sums
  {
    int r = tid >> 2, sub = tid & 3;
    float s = 0.f, sq = 0.f;
    #pragma unroll
    for (int i = 0; i < 32; ++i) {
      float v = xs[r][sub * 32 + i];
      s += v; sq += v * v;
    }
    s  += __shfl_xor(s, 1);  s  += __shfl_xor(s, 2);
    sq += __shfl_xor(sq, 1); sq += __shfl_xor(sq, 2);
    float mean = s * (1.f / 128.f);
    float var  = sq * (1.f / 128.f) - mean * mean;
    float rstd = rsqrtf(var + 1e-3f);
    #pragma unroll
    for (int i = 0; i < 32; ++i) {
      int c = sub * 32 + i;
      float v = (xs[r][c] - mean) * rstd * gamma[c] + beta[c];
      xn[r][c] = __float2bfloat16(v);
    }
  }
  __syncthreads();

  // MFMA projections: wave w owns rows [w*16, w*16+16), all 256 output cols
  int w = tid >> 6, lane = tid & 63, lr = lane & 15, lh = lane >> 4;

  short8 a[4];
  #pragma unroll
  for (int h = 0; h < 4; ++h)
    a[h] = *reinterpret_cast<const short8*>(&xn[w * 16 + lr][h * 32 + lh * 8]);

  const f32x4 fzero = {0.f, 0.f, 0.f, 0.f};
  // Q/K region: ct 0..7
  #pragma unroll
  for (int ct = 0; ct < 8; ++ct) {
    f32x4 acc = fzero;
    #pragma unroll
    for (int h = 0; h < 4; ++h) {
      short8 bf = *reinterpret_cast<const short8*>(
          &wt[(ct * 16 + lr) * 128 + h * 32 + lh * 8]);
      acc = __builtin_amdgcn_mfma_f32_16x16x32_bf16(a[h], bf, acc, 0, 0, 0);
    }
    int col = ct * 16 + lr;             // D-layout: col = lane&15
    int nb  = n0 + w * 16 + lh * 4;     // D-layout: row = (lane>>4)*4 + r
    #pragma unroll
    for (int r = 0; r < 4; ++r) {
      int n = nb + r;
      __hip_bfloat16 val = __float2bfloat16(acc[r]);
      if (col < 64)
        q[((size_t)bm * N_ + n) * D_ + col] = val;
      else
        k[((size_t)bm * N_ + n) * D_ + (col - 64)] = val;
    }
  }
  // V region: ct 8..15 -> vt[bm][c][n], 4 consecutive n pack to b64
  #pragma unroll
  for (int ct = 8; ct < 16; ++ct) {
    f32x4 acc = fzero;
    #pragma unroll
    for (int h = 0; h < 4; ++h) {
      short8 bf = *reinterpret_cast<const short8*>(
          &wt[(ct * 16 + lr) * 128 + h * 32 + lh * 8]);
      acc = __builtin_amdgcn_mfma_f32_16x16x32_bf16(a[h], bf, acc, 0, 0, 0);
    }
    int c  = ct * 16 + lr - 128;
    int nb = n0 + w * 16 + lh * 4;
    alignas(8) __hip_bfloat16 tmp[4];
    #pragma unroll
    for (int r = 0; r < 4; ++r) tmp[r] = __float2bfloat16(acc[r]);
    *reinterpret_cast<short4v*>(&vt[((size_t)bm * C_ + c) * N_ + nb]) =
        *reinterpret_cast<const short4v*>(tmp);
  }
}

// ---------------------------------------------------------------------------
// Kernel 2: flash attention per (b,m), swapped-QK^T (S^T via mfma(K,Q)) so
// softmax rows are lane-local. Grid: 128 bm * 8 tiles of 128 q-rows.
// Block 256 = 4 waves, each wave 32 q-rows (32x32x16 MFMAs). KV tile 64.
// Defer-max online softmax (THR=8, exp2 domain; scale folded into w_q).
// ---------------------------------------------------------------------------
__global__ __launch_bounds__(256, 3) void attn_kernel(
    const float* __restrict__ x, const float* __restrict__ lam,
    const __hip_bfloat16* __restrict__ q, const __hip_bfloat16* __restrict__ k,
    const __hip_bfloat16* __restrict__ vt, float* __restrict__ out) {
  __shared__ alignas(16) __hip_bfloat16 kt[64 * 72];        // K tile [kj][d]
  __shared__ alignas(16) __hip_bfloat16 vtt[128 * 72];      // V^T tile [c][kj]
  __shared__ alignas(16) __hip_bfloat16 pt[4][32 * 72];     // per-wave P [q][kj]

  int bid = blockIdx.x;
  int bm  = bid >> 3;
  int n0  = (bid & 7) * 128;
  int b   = bm >> 5, m = bm & 31;
  int tid = threadIdx.x;
  int w = tid >> 6, l = tid & 63;
  int lq = l & 31, hi = l >> 5;

  // Q fragments (B operand of S^T): lane = col q, k = d = 16*s + 8*hi + i
  short8 qf[4];
  {
    int n = n0 + w * 32 + lq;
    const __hip_bfloat16* qp = q + ((size_t)bm * N_ + n) * D_;
    #pragma unroll
    for (int s = 0; s < 4; ++s)
      qf[s] = *reinterpret_cast<const short8*>(qp + s * 16 + hi * 8);
  }

  f32x16 acc[4];
  const f32x16 z16 = {0.f,0.f,0.f,0.f,0.f,0.f,0.f,0.f,
                      0.f,0.f,0.f,0.f,0.f,0.f,0.f,0.f};
  #pragma unroll
  for (int ct = 0; ct < 4; ++ct) acc[ct] = z16;
  float m_run = -1e30f, l_run = 0.f;

  for (int t = 0; t < 16; ++t) {
    int j0 = t * 64;
    // ---- stage K tile (64x64) and V^T tile (128x64), stride 72 ----
    #pragma unroll
    for (int i = 0; i < 2; ++i) {
      int ch = tid + i * 256;            // 512 chunks of 16B
      int r = ch >> 3, c = ch & 7;
      short8 v = *reinterpret_cast<const short8*>(
          &k[((size_t)bm * N_ + j0 + r) * D_ + c * 8]);
      *reinterpret_cast<short8*>(&kt[r * 72 + c * 8]) = v;
    }
    #pragma unroll
    for (int i = 0; i < 4; ++i) {
      int ch = tid + i * 256;            // 1024 chunks of 16B
      int r = ch >> 3, c = ch & 7;
      short8 v = *reinterpret_cast<const short8*>(
          &vt[((size_t)bm * C_ + r) * N_ + j0 + c * 8]);
      *reinterpret_cast<short8*>(&vtt[r * 72 + c * 8]) = v;
    }
    __syncthreads();

    // ---- S^T = K * Q^T : st[t32] holds kj rows (reg-local), q cols (lane)
    f32x16 st[2];
    st[0] = z16; st[1] = z16;
    #pragma unroll
    for (int s = 0; s < 4; ++s) {
      short8 kf0 = *reinterpret_cast<const short8*>(&kt[lq * 72 + s * 16 + hi * 8]);
      st[0] = __builtin_amdgcn_mfma_f32_32x32x16_bf16(kf0, qf[s], st[0], 0, 0, 0);
      short8 kf1 = *reinterpret_cast<const short8*>(&kt[(32 + lq) * 72 + s * 16 + hi * 8]);
      st[1] = __builtin_amdgcn_mfma_f32_32x32x16_bf16(kf1, qf[s], st[1], 0, 0, 0);
    }

    // ---- in-register online softmax (q = lq lane-local rows) ----
    float mx;
    {
      float t8[8];
      #pragma unroll
      for (int i = 0; i < 8; ++i)
        t8[i] = fmaxf(fmaxf(st[0][i], st[0][i + 8]), fmaxf(st[1][i], st[1][i + 8]));
      float a0 = fmaxf(fmaxf(t8[0], t8[1]), fmaxf(t8[2], t8[3]));
      float a1 = fmaxf(fmaxf(t8[4], t8[5]), fmaxf(t8[6], t8[7]));
      mx = fmaxf(a0, a1);
      mx = fmaxf(mx, __shfl_xor(mx, 32));   // combine the two hi halves
    }
    // defer-max gate: rescale only if max grew past THR=8 (exp2 domain)
    if (__any(mx > m_run + 8.0f)) {
      float mnew = fmaxf(m_run, mx);
      float fac = EXP2(m_run - mnew);
      l_run *= fac;
      m_run = mnew;
      #pragma unroll
      for (int reg = 0; reg < 16; ++reg) {
        int qi = (reg & 3) + 8 * (reg >> 2) + 4 * hi;
        float f = __shfl(fac, qi);
        #pragma unroll
        for (int ct = 0; ct < 4; ++ct) acc[ct][reg] *= f;
      }
    }
    // p = exp2(s - m_run), in place; sum via tree
    #pragma unroll
    for (int i = 0; i < 16; ++i) {
      st[0][i] = EXP2(st[0][i] - m_run);
      st[1][i] = EXP2(st[1][i] - m_run);
    }
    {
      float s8[8];
      #pragma unroll
      for (int i = 0; i < 8; ++i)
        s8[i] = (st[0][i] + st[0][i + 8]) + (st[1][i] + st[1][i + 8]);
      float a0 = (s8[0] + s8[1]) + (s8[2] + s8[3]);
      float a1 = (s8[4] + s8[5]) + (s8[6] + s8[7]);
      float rs = a0 + a1;
      rs += __shfl_xor(rs, 32);
      l_run += rs;
    }

    // ---- pack P to bf16, per-wave LDS roundtrip (b64 writes: 4 consec kj)
    #pragma unroll
    for (int t32 = 0; t32 < 2; ++t32) {
      #pragma unroll
      for (int h = 0; h < 4; ++h) {
        alignas(8) __hip_bfloat16 tmp[4];
        #pragma unroll
        for (int j = 0; j < 4; ++j)
          tmp[j] = __float2bfloat16(st[t32][4 * h + j]);
        *reinterpret_cast<short4v*>(
            &pt[w][lq * 72 + 8 * h + 4 * hi + 32 * t32]) =
            *reinterpret_cast<const short4v*>(tmp);
      }
    }

    // ---- O += P @ V : A = P-frag (row q = lq), B = V-frag (col c = lq)
    #pragma unroll
    for (int kb = 0; kb < 4; ++kb) {
      short8 pf = *reinterpret_cast<const short8*>(
          &pt[w][lq * 72 + kb * 16 + hi * 8]);
      #pragma unroll
      for (int ct = 0; ct < 4; ++ct) {
        short8 vf = *reinterpret_cast<const short8*>(
            &vtt[(ct * 32 + lq) * 72 + kb * 16 + hi * 8]);
        acc[ct] = __builtin_amdgcn_mfma_f32_32x32x16_bf16(pf, vf, acc[ct], 0, 0, 0);
      }
    }
    __syncthreads();
  }

  // ---- epilogue: out = x + (O / l) * lam  (acc rows q = D-layout) ----
  float inv = 1.0f / l_run;        // lane's q = lq
  float rlv[16];
  #pragma unroll
  for (int reg = 0; reg < 16; ++reg) {
    int qi = (reg & 3) + 8 * (reg >> 2) + 4 * hi;
    rlv[reg] = __shfl(inv, qi);
  }
  #pragma unroll
  for (int ct = 0; ct < 4; ++ct) {
    int c = ct * 32 + lq;
    float lamc = lam[c];
    #pragma unroll
    for (int reg = 0; reg < 16; ++reg) {
      int qi = (reg & 3) + 8 * (reg >> 2) + 4 * hi;
      int n = n0 + w * 32 + qi;
      size_t idx = ((((size_t)b * N_ + n) * M_ + m) * C_) + c;
      out[idx] = x[idx] + acc[ct][reg] * rlv[reg] * lamc;
    }
  }
}

// ---------------------------------------------------------------------------
extern "C" void kernel_launch(void* const* d_in, const int* in_sizes, int n_in,
                              void* d_out, int out_size, void* d_ws, size_t ws_size,
                              hipStream_t stream) {
  const float* x     = (const float*)d_in[0];
  const float* gamma = (const float*)d_in[1];
  const float* beta  = (const float*)d_in[2];
  const float* wq    = (const float*)d_in[3];
  const float* wk    = (const float*)d_in[4];
  const float* wv    = (const float*)d_in[5];
  const float* lam   = (const float*)d_in[6];
  float* out = (float*)d_out;

  __hip_bfloat16* ws = (__hip_bfloat16*)d_ws;
  __hip_bfloat16* wt = ws;                        // 256*128
  __hip_bfloat16* q  = wt + 256 * 128;            // 128*1024*64
  __hip_bfloat16* k  = q + (size_t)BM_ * N_ * D_; // 128*1024*64
  __hip_bfloat16* vt = k + (size_t)BM_ * N_ * D_; // 128*128*1024 (transposed)

  prep_weights<<<128, 256, 0, stream>>>(wq, wk, wv, wt);
  ln_qkv<<<BM_ * (N_ / 64), 256, 0, stream>>>(x, gamma, beta, wt, q, k, vt);
  attn_kernel<<<BM_ * (N_ / 128), 256, 0, stream>>>(x, lam, q, k, vt, out);
}

// Round 3
// 169.700 us; speedup vs baseline: 1.7443x; 1.2875x over previous
//
#include <hip/hip_runtime.h>
#include <hip/hip_bf16.h>

#define B_ 4
#define N_ 1024
#define M_ 32
#define C_ 128
#define D_ 64
#define BM_ (B_*M_)   // 128 independent attention problems

typedef float f32x4 __attribute__((ext_vector_type(4)));
typedef float f32x16 __attribute__((ext_vector_type(16)));
typedef short short8 __attribute__((ext_vector_type(8)));
typedef short short4v __attribute__((ext_vector_type(4)));

#define EXP2(x) __builtin_amdgcn_exp2f(x)

static __device__ __forceinline__ int cvtpk_bf16(float lo, float hi) {
  int r;
  asm("v_cvt_pk_bf16_f32 %0, %1, %2" : "=v"(r) : "v"(lo), "v"(hi));
  return r;
}
static __device__ __forceinline__ void plswap(int& a, int& b) {
  asm("v_permlane32_swap_b32 %0, %1" : "+v"(a), "+v"(b));
}

// ---------------------------------------------------------------------------
// Kernel 0: transpose weights to bf16, concatenated [256 cols][128 k].
// cols 0-63 = w_q scaled by (1/sqrt(64))*log2(e)  (exp2-domain softmax),
// 64-127 = w_k, 128-255 = w_v.
// ---------------------------------------------------------------------------
__global__ __launch_bounds__(256) void prep_weights(
    const float* __restrict__ wq, const float* __restrict__ wk,
    const float* __restrict__ wv, __hip_bfloat16* __restrict__ wt) {
  int idx = blockIdx.x * 256 + threadIdx.x;   // 0 .. 32767
  int col = idx >> 7;      // 0..255
  int kk  = idx & 127;     // 0..127
  float v;
  if (col < 64)        v = wq[kk * 64 + col] * (0.125f * 1.44269504088896f);
  else if (col < 128)  v = wk[kk * 64 + (col - 64)];
  else                 v = wv[kk * 128 + (col - 128)];
  wt[col * 128 + kk] = __float2bfloat16(v);
}

// ---------------------------------------------------------------------------
// Kernel 1: LayerNorm (over C) + Q/K/V projections via MFMA.
// Grid: 128 (b,m) * 16 row-tiles of 64. Block: 256 threads (4 waves).
// Q,K stored [bm][N][64] bf16; V stored transposed [bm][C][N] bf16.
// ---------------------------------------------------------------------------
__global__ __launch_bounds__(256) void ln_qkv(
    const float* __restrict__ x, const float* __restrict__ gamma,
    const float* __restrict__ beta, const __hip_bfloat16* __restrict__ wt,
    __hip_bfloat16* __restrict__ q, __hip_bfloat16* __restrict__ k,
    __hip_bfloat16* __restrict__ vt) {
  __shared__ float xs[64][128];                       // 32 KB
  __shared__ alignas(16) __hip_bfloat16 xn[64][136];  // +8 pad (16B multiple)

  int bid = blockIdx.x;
  int bm  = bid >> 4;
  int n0  = (bid & 15) * 64;
  int b   = bm >> 5, m = bm & 31;
  int tid = threadIdx.x;

  // stage x rows [n0, n0+64) for fixed (b,m): coalesced float4
  const float* xbase = x + ((((size_t)b * N_ + n0) * M_ + m) * C_);
  #pragma unroll
  for (int it = 0; it < 8; ++it) {
    int f4 = it * 256 + tid;        // 0..2047 float4 units
    int r = f4 >> 5, c4 = f4 & 31;
    float4 v = *reinterpret_cast<const float4*>(xbase + (size_t)r * (M_ * C_) + c4 * 4);
    *reinterpret_cast<float4*>(&xs[r][c4 * 4]) = v;
  }
  __syncthreads();

  // LayerNorm: 4 threads per row (same wave), shfl-combine partial sums
  {
    int r = tid >> 2, sub = tid & 3;
    float s = 0.f, sq = 0.f;
    #pragma unroll
    for (int i = 0; i < 32; ++i) {
      float v = xs[r][sub * 32 + i];
      s += v; sq += v * v;
    }
    s  += __shfl_xor(s, 1);  s  += __shfl_xor(s, 2);
    sq += __shfl_xor(sq, 1); sq += __shfl_xor(sq, 2);
    float mean = s * (1.f / 128.f);
    float var  = sq * (1.f / 128.f) - mean * mean;
    float rstd = rsqrtf(var + 1e-3f);
    #pragma unroll
    for (int i = 0; i < 32; ++i) {
      int c = sub * 32 + i;
      float v = (xs[r][c] - mean) * rstd * gamma[c] + beta[c];
      xn[r][c] = __float2bfloat16(v);
    }
  }
  __syncthreads();

  // MFMA projections: wave w owns rows [w*16, w*16+16), all 256 output cols
  int w = tid >> 6, lane = tid & 63, lr = lane & 15, lh = lane >> 4;

  short8 a[4];
  #pragma unroll
  for (int h = 0; h < 4; ++h)
    a[h] = *reinterpret_cast<const short8*>(&xn[w * 16 + lr][h * 32 + lh * 8]);

  const f32x4 fzero = {0.f, 0.f, 0.f, 0.f};
  // Q/K region: ct 0..7
  #pragma unroll
  for (int ct = 0; ct < 8; ++ct) {
    f32x4 acc = fzero;
    #pragma unroll
    for (int h = 0; h < 4; ++h) {
      short8 bf = *reinterpret_cast<const short8*>(
          &wt[(ct * 16 + lr) * 128 + h * 32 + lh * 8]);
      acc = __builtin_amdgcn_mfma_f32_16x16x32_bf16(a[h], bf, acc, 0, 0, 0);
    }
    int col = ct * 16 + lr;             // D-layout: col = lane&15
    int nb  = n0 + w * 16 + lh * 4;     // D-layout: row = (lane>>4)*4 + r
    #pragma unroll
    for (int r = 0; r < 4; ++r) {
      int n = nb + r;
      __hip_bfloat16 val = __float2bfloat16(acc[r]);
      if (col < 64)
        q[((size_t)bm * N_ + n) * D_ + col] = val;
      else
        k[((size_t)bm * N_ + n) * D_ + (col - 64)] = val;
    }
  }
  // V region: ct 8..15 -> vt[bm][c][n], 4 consecutive n pack to b64
  #pragma unroll
  for (int ct = 8; ct < 16; ++ct) {
    f32x4 acc = fzero;
    #pragma unroll
    for (int h = 0; h < 4; ++h) {
      short8 bf = *reinterpret_cast<const short8*>(
          &wt[(ct * 16 + lr) * 128 + h * 32 + lh * 8]);
      acc = __builtin_amdgcn_mfma_f32_16x16x32_bf16(a[h], bf, acc, 0, 0, 0);
    }
    int c  = ct * 16 + lr - 128;
    int nb = n0 + w * 16 + lh * 4;
    alignas(8) __hip_bfloat16 tmp[4];
    #pragma unroll
    for (int r = 0; r < 4; ++r) tmp[r] = __float2bfloat16(acc[r]);
    *reinterpret_cast<short4v*>(&vt[((size_t)bm * C_ + c) * N_ + nb]) =
        *reinterpret_cast<const short4v*>(tmp);
  }
}

// ---------------------------------------------------------------------------
// Kernel 2: flash attention per (b,m), swapped-QK^T, fully in-register P
// (cvt_pk_bf16 + permlane32_swap), single-barrier double-buffered K/V
// pipeline (loads issued before compute, ds_write after).
// Grid: 128 bm * 8 tiles of 128 q-rows. Block 256 = 4 waves x 32 q-rows.
// ---------------------------------------------------------------------------
__global__ __launch_bounds__(256, 2) void attn_kernel(
    const float* __restrict__ x, const float* __restrict__ lam,
    const __hip_bfloat16* __restrict__ q, const __hip_bfloat16* __restrict__ k,
    const __hip_bfloat16* __restrict__ vt, float* __restrict__ out) {
  __shared__ alignas(16) __hip_bfloat16 kbuf[2][64 * 72];   // 9216 B each
  __shared__ alignas(16) __hip_bfloat16 vbuf[2][128 * 72];  // 18432 B each

  int bid = blockIdx.x;
  int bm  = bid >> 3;
  int n0  = (bid & 7) * 128;
  int b   = bm >> 5, m = bm & 31;
  int tid = threadIdx.x;
  int w = tid >> 6, l = tid & 63;
  int lq = l & 31, hi = l >> 5;

  const __hip_bfloat16* kbase = k + (size_t)bm * N_ * D_;
  const __hip_bfloat16* vbase = vt + (size_t)bm * C_ * N_;

  // staging chunk coords (16B chunks)
  int kr0 = tid >> 3,          kc0 = tid & 7;          // K chunks tid, tid+256
  int kr1 = (tid + 256) >> 3,  kc1 = tid & 7;
  int vr[4], vc = tid & 7;
  #pragma unroll
  for (int i = 0; i < 4; ++i) vr[i] = (tid + i * 256) >> 3;

  // Q fragments (B operand of S^T): lane = col q, k = d = 16*s + 8*hi + i
  short8 qf[4];
  {
    int n = n0 + w * 32 + lq;
    const __hip_bfloat16* qp = q + ((size_t)bm * N_ + n) * D_;
    #pragma unroll
    for (int s = 0; s < 4; ++s)
      qf[s] = *reinterpret_cast<const short8*>(qp + s * 16 + hi * 8);
  }

  f32x16 acc[4];
  const f32x16 z16 = {0.f,0.f,0.f,0.f,0.f,0.f,0.f,0.f,
                      0.f,0.f,0.f,0.f,0.f,0.f,0.f,0.f};
  #pragma unroll
  for (int ct = 0; ct < 4; ++ct) acc[ct] = z16;
  float m_run = -1e30f, l_run = 0.f;

  short8 kreg[2], vreg[4];
  // ---- prologue: stage tile 0 into buf 0 ----
  kreg[0] = *reinterpret_cast<const short8*>(&kbase[(size_t)kr0 * D_ + kc0 * 8]);
  kreg[1] = *reinterpret_cast<const short8*>(&kbase[(size_t)kr1 * D_ + kc1 * 8]);
  #pragma unroll
  for (int i = 0; i < 4; ++i)
    vreg[i] = *reinterpret_cast<const short8*>(&vbase[(size_t)vr[i] * N_ + vc * 8]);
  *reinterpret_cast<short8*>(&kbuf[0][kr0 * 72 + kc0 * 8]) = kreg[0];
  *reinterpret_cast<short8*>(&kbuf[0][kr1 * 72 + kc1 * 8]) = kreg[1];
  #pragma unroll
  for (int i = 0; i < 4; ++i)
    *reinterpret_cast<short8*>(&vbuf[0][vr[i] * 72 + vc * 8]) = vreg[i];
  __syncthreads();

  for (int t = 0; t < 16; ++t) {
    int cur = t & 1;
    // ---- issue next tile's global loads (latency hides under compute) ----
    if (t < 15) {
      int j0n = (t + 1) * 64;
      kreg[0] = *reinterpret_cast<const short8*>(&kbase[(size_t)(j0n + kr0) * D_ + kc0 * 8]);
      kreg[1] = *reinterpret_cast<const short8*>(&kbase[(size_t)(j0n + kr1) * D_ + kc1 * 8]);
      #pragma unroll
      for (int i = 0; i < 4; ++i)
        vreg[i] = *reinterpret_cast<const short8*>(&vbase[(size_t)vr[i] * N_ + j0n + vc * 8]);
    }

    const __hip_bfloat16* kt  = kbuf[cur];
    const __hip_bfloat16* vtt = vbuf[cur];

    // ---- S^T = K * Q^T : st[t32] holds kj rows (reg-local), q cols (lane)
    f32x16 st[2];
    st[0] = z16; st[1] = z16;
    #pragma unroll
    for (int s = 0; s < 4; ++s) {
      short8 kf0 = *reinterpret_cast<const short8*>(&kt[lq * 72 + s * 16 + hi * 8]);
      st[0] = __builtin_amdgcn_mfma_f32_32x32x16_bf16(kf0, qf[s], st[0], 0, 0, 0);
      short8 kf1 = *reinterpret_cast<const short8*>(&kt[(32 + lq) * 72 + s * 16 + hi * 8]);
      st[1] = __builtin_amdgcn_mfma_f32_32x32x16_bf16(kf1, qf[s], st[1], 0, 0, 0);
    }

    // ---- in-register online softmax (q = lq lane-local) ----
    float mx;
    {
      float t8[8];
      #pragma unroll
      for (int i = 0; i < 8; ++i)
        t8[i] = fmaxf(fmaxf(st[0][i], st[0][i + 8]), fmaxf(st[1][i], st[1][i + 8]));
      float a0 = fmaxf(fmaxf(t8[0], t8[1]), fmaxf(t8[2], t8[3]));
      float a1 = fmaxf(fmaxf(t8[4], t8[5]), fmaxf(t8[6], t8[7]));
      mx = fmaxf(a0, a1);
      mx = fmaxf(mx, __shfl_xor(mx, 32));
    }
    if (__any(mx > m_run + 8.0f)) {     // defer-max gate (exp2 domain, THR=8)
      float mnew = fmaxf(m_run, mx);
      float fac = EXP2(m_run - mnew);
      l_run *= fac;
      m_run = mnew;
      #pragma unroll
      for (int reg = 0; reg < 16; ++reg) {
        int qi = (reg & 3) + 8 * (reg >> 2) + 4 * hi;
        float f = __shfl(fac, qi);
        #pragma unroll
        for (int ct = 0; ct < 4; ++ct) acc[ct][reg] *= f;
      }
    }
    #pragma unroll
    for (int i = 0; i < 16; ++i) {
      st[0][i] = EXP2(st[0][i] - m_run);
      st[1][i] = EXP2(st[1][i] - m_run);
    }
    {
      float s8[8];
      #pragma unroll
      for (int i = 0; i < 8; ++i)
        s8[i] = (st[0][i] + st[0][i + 8]) + (st[1][i] + st[1][i + 8]);
      float rs = ((s8[0] + s8[1]) + (s8[2] + s8[3])) +
                 ((s8[4] + s8[5]) + (s8[6] + s8[7]));
      rs += __shfl_xor(rs, 32);
      l_run += rs;
    }

    // ---- build PV A-fragments fully in-register (cvt_pk + permlane) ----
    // lane (q=lq, half h) holds st[t32] regs mapping kj=(r&3)+8*(r>>2)+4h.
    // frag for kb needs kj = kb*16 + h*8 + j, j=0..7.
    union W4 { int w[4]; short8 s8; } pf[4];
    #pragma unroll
    for (int t32 = 0; t32 < 2; ++t32) {
      int A = cvtpk_bf16(st[t32][0], st[t32][1]);
      int Bw = cvtpk_bf16(st[t32][2], st[t32][3]);
      int Cw = cvtpk_bf16(st[t32][4], st[t32][5]);
      int Dw = cvtpk_bf16(st[t32][6], st[t32][7]);
      plswap(A, Cw);   // A -> W0, Cw -> W2
      plswap(Bw, Dw);  // Bw -> W1, Dw -> W3
      pf[t32 * 2].w[0] = A;  pf[t32 * 2].w[1] = Bw;
      pf[t32 * 2].w[2] = Cw; pf[t32 * 2].w[3] = Dw;
      int E = cvtpk_bf16(st[t32][8], st[t32][9]);
      int F = cvtpk_bf16(st[t32][10], st[t32][11]);
      int G = cvtpk_bf16(st[t32][12], st[t32][13]);
      int H = cvtpk_bf16(st[t32][14], st[t32][15]);
      plswap(E, G);
      plswap(F, H);
      pf[t32 * 2 + 1].w[0] = E; pf[t32 * 2 + 1].w[1] = F;
      pf[t32 * 2 + 1].w[2] = G; pf[t32 * 2 + 1].w[3] = H;
    }

    // ---- O += P @ V ----
    #pragma unroll
    for (int kb = 0; kb < 4; ++kb) {
      #pragma unroll
      for (int ct = 0; ct < 4; ++ct) {
        short8 vf = *reinterpret_cast<const short8*>(
            &vtt[(ct * 32 + lq) * 72 + kb * 16 + hi * 8]);
        acc[ct] = __builtin_amdgcn_mfma_f32_32x32x16_bf16(pf[kb].s8, vf, acc[ct], 0, 0, 0);
      }
    }

    // ---- write staged regs into the other buffer, one barrier per tile ----
    if (t < 15) {
      int nxt = cur ^ 1;
      *reinterpret_cast<short8*>(&kbuf[nxt][kr0 * 72 + kc0 * 8]) = kreg[0];
      *reinterpret_cast<short8*>(&kbuf[nxt][kr1 * 72 + kc1 * 8]) = kreg[1];
      #pragma unroll
      for (int i = 0; i < 4; ++i)
        *reinterpret_cast<short8*>(&vbuf[nxt][vr[i] * 72 + vc * 8]) = vreg[i];
      __syncthreads();
    }
  }

  // ---- epilogue: out = x + (O / l) * lam ----
  float inv = 1.0f / l_run;        // lane's q = lq
  float rlv[16];
  #pragma unroll
  for (int reg = 0; reg < 16; ++reg) {
    int qi = (reg & 3) + 8 * (reg >> 2) + 4 * hi;
    rlv[reg] = __shfl(inv, qi);
  }
  #pragma unroll
  for (int ct = 0; ct < 4; ++ct) {
    int c = ct * 32 + lq;
    float lamc = lam[c];
    #pragma unroll
    for (int reg = 0; reg < 16; ++reg) {
      int qi = (reg & 3) + 8 * (reg >> 2) + 4 * hi;
      int n = n0 + w * 32 + qi;
      size_t idx = ((((size_t)b * N_ + n) * M_ + m) * C_) + c;
      out[idx] = x[idx] + acc[ct][reg] * rlv[reg] * lamc;
    }
  }
}

// ---------------------------------------------------------------------------
extern "C" void kernel_launch(void* const* d_in, const int* in_sizes, int n_in,
                              void* d_out, int out_size, void* d_ws, size_t ws_size,
                              hipStream_t stream) {
  const float* x     = (const float*)d_in[0];
  const float* gamma = (const float*)d_in[1];
  const float* beta  = (const float*)d_in[2];
  const float* wq    = (const float*)d_in[3];
  const float* wk    = (const float*)d_in[4];
  const float* wv    = (const float*)d_in[5];
  const float* lam   = (const float*)d_in[6];
  float* out = (float*)d_out;

  __hip_bfloat16* ws = (__hip_bfloat16*)d_ws;
  __hip_bfloat16* wt = ws;                        // 256*128
  __hip_bfloat16* q  = wt + 256 * 128;            // 128*1024*64
  __hip_bfloat16* k  = q + (size_t)BM_ * N_ * D_; // 128*1024*64
  __hip_bfloat16* vt = k + (size_t)BM_ * N_ * D_; // 128*128*1024 (transposed)

  prep_weights<<<128, 256, 0, stream>>>(wq, wk, wv, wt);
  ln_qkv<<<BM_ * (N_ / 64), 256, 0, stream>>>(x, gamma, beta, wt, q, k, vt);
  attn_kernel<<<BM_ * (N_ / 128), 256, 0, stream>>>(x, lam, q, k, vt, out);
}

// Round 4
// 111.685 us; speedup vs baseline: 2.6504x; 1.5195x over previous
//
#include <hip/hip_runtime.h>
#include <hip/hip_bf16.h>

#define B_ 4
#define N_ 1024
#define M_ 32
#define C_ 128
#define D_ 64
#define BM_ (B_*M_)   // 128 independent attention problems

typedef float f32x4 __attribute__((ext_vector_type(4)));
typedef float f32x16 __attribute__((ext_vector_type(16)));
typedef short short8 __attribute__((ext_vector_type(8)));
typedef short short4v __attribute__((ext_vector_type(4)));

#define EXP2(x) __builtin_amdgcn_exp2f(x)

static __device__ __forceinline__ int cvtpk_bf16(float lo, float hi) {
  int r;
  asm("v_cvt_pk_bf16_f32 %0, %1, %2" : "=v"(r) : "v"(lo), "v"(hi));
  return r;
}
static __device__ __forceinline__ void plswap(int& a, int& b) {
  asm("v_permlane32_swap_b32 %0, %1" : "+v"(a), "+v"(b));
}

// ---------------------------------------------------------------------------
// Kernel 0: transpose weights to bf16, concatenated [256 cols][128 k].
// cols 0-63 = w_q scaled by (1/sqrt(64))*log2(e)  (exp2-domain softmax),
// 64-127 = w_k, 128-255 = w_v.
// ---------------------------------------------------------------------------
__global__ __launch_bounds__(256) void prep_weights(
    const float* __restrict__ wq, const float* __restrict__ wk,
    const float* __restrict__ wv, __hip_bfloat16* __restrict__ wt) {
  int idx = blockIdx.x * 256 + threadIdx.x;   // 0 .. 32767
  int col = idx >> 7;      // 0..255
  int kk  = idx & 127;     // 0..127
  float v;
  if (col < 64)        v = wq[kk * 64 + col] * (0.125f * 1.44269504088896f);
  else if (col < 128)  v = wk[kk * 64 + (col - 64)];
  else                 v = wv[kk * 128 + (col - 128)];
  wt[col * 128 + kk] = __float2bfloat16(v);
}

// ---------------------------------------------------------------------------
// Kernel 1: LayerNorm (register-based, no f32 LDS stage) + Q/K/V projections.
// Grid: 128 (b,m) * 8 row-tiles of 128. Block: 512 threads (8 waves).
// Wave w computes column-tiles {w, w+8} for ALL 128 rows -> wt fragments
// loaded once per wave. Q,K stored [bm][N][64]; V transposed [bm][C][N].
// ---------------------------------------------------------------------------
__global__ __launch_bounds__(512, 6) void ln_qkv(
    const float* __restrict__ x, const float* __restrict__ gamma,
    const float* __restrict__ beta, const __hip_bfloat16* __restrict__ wt,
    __hip_bfloat16* __restrict__ q, __hip_bfloat16* __restrict__ k,
    __hip_bfloat16* __restrict__ vt) {
  __shared__ alignas(16) __hip_bfloat16 xn[128][136];  // 34.8 KB

  int bid = blockIdx.x;
  int bm  = bid >> 3;
  int n0  = (bid & 7) * 128;
  int b   = bm >> 5, m = bm & 31;
  int tid = threadIdx.x;

  // ---- load 8 float4 chunks (coalesced); chunk column is tid&31 for all ----
  const float* xbase = x + ((((size_t)b * N_ + n0) * M_ + m) * C_);
  int c4 = tid & 31;
  float4 vch[8];
  #pragma unroll
  for (int it = 0; it < 8; ++it) {
    int r = (it * 512 + tid) >> 5;
    vch[it] = *reinterpret_cast<const float4*>(xbase + (size_t)r * (M_ * C_) + c4 * 4);
  }
  float4 g4 = *reinterpret_cast<const float4*>(gamma + c4 * 4);
  float4 b4 = *reinterpret_cast<const float4*>(beta + c4 * 4);

  // ---- per-row LayerNorm: reduce across the 32-lane group owning the row ----
  #pragma unroll
  for (int it = 0; it < 8; ++it) {
    int r = (it * 512 + tid) >> 5;
    float4 v = vch[it];
    float s  = (v.x + v.y) + (v.z + v.w);
    float sq = (v.x * v.x + v.y * v.y) + (v.z * v.z + v.w * v.w);
    s  += __shfl_xor(s, 1);  sq += __shfl_xor(sq, 1);
    s  += __shfl_xor(s, 2);  sq += __shfl_xor(sq, 2);
    s  += __shfl_xor(s, 4);  sq += __shfl_xor(sq, 4);
    s  += __shfl_xor(s, 8);  sq += __shfl_xor(sq, 8);
    s  += __shfl_xor(s, 16); sq += __shfl_xor(sq, 16);
    float mean = s * (1.f / 128.f);
    float var  = sq * (1.f / 128.f) - mean * mean;
    float rstd = rsqrtf(var + 1e-3f);
    alignas(8) __hip_bfloat16 tmp[4];
    tmp[0] = __float2bfloat16((v.x - mean) * rstd * g4.x + b4.x);
    tmp[1] = __float2bfloat16((v.y - mean) * rstd * g4.y + b4.y);
    tmp[2] = __float2bfloat16((v.z - mean) * rstd * g4.z + b4.z);
    tmp[3] = __float2bfloat16((v.w - mean) * rstd * g4.w + b4.w);
    *reinterpret_cast<short4v*>(&xn[r][c4 * 4]) =
        *reinterpret_cast<const short4v*>(tmp);
  }
  __syncthreads();

  // ---- projections: wave w -> col tiles ct0=w (Q/K), ct1=w+8 (V) ----
  int w = tid >> 6, l = tid & 63, lr = l & 15, lh = l >> 4;
  int ct0 = w, ct1 = w + 8;

  short8 wf0[4], wf1[4];
  #pragma unroll
  for (int h = 0; h < 4; ++h) {
    wf0[h] = *reinterpret_cast<const short8*>(
        &wt[(ct0 * 16 + lr) * 128 + h * 32 + lh * 8]);
    wf1[h] = *reinterpret_cast<const short8*>(
        &wt[(ct1 * 16 + lr) * 128 + h * 32 + lh * 8]);
  }

  const f32x4 fzero = {0.f, 0.f, 0.f, 0.f};
  int col0 = ct0 * 16 + lr;          // 0..127 (Q if <64 else K) — wave-uniform split
  int cV   = w * 16 + lr;            // V output channel (ct1*16+lr-128)
  #pragma unroll
  for (int rt = 0; rt < 8; ++rt) {
    short8 a[4];
    #pragma unroll
    for (int h = 0; h < 4; ++h)
      a[h] = *reinterpret_cast<const short8*>(&xn[rt * 16 + lr][h * 32 + lh * 8]);
    f32x4 acc0 = fzero, acc1 = fzero;
    #pragma unroll
    for (int h = 0; h < 4; ++h) {
      acc0 = __builtin_amdgcn_mfma_f32_16x16x32_bf16(a[h], wf0[h], acc0, 0, 0, 0);
      acc1 = __builtin_amdgcn_mfma_f32_16x16x32_bf16(a[h], wf1[h], acc1, 0, 0, 0);
    }
    int nb = n0 + rt * 16 + lh * 4;
    // Q/K store (scalar bf16; layout [n][d])
    if (ct0 < 4) {
      #pragma unroll
      for (int r = 0; r < 4; ++r)
        q[((size_t)bm * N_ + nb + r) * D_ + col0] = __float2bfloat16(acc0[r]);
    } else {
      #pragma unroll
      for (int r = 0; r < 4; ++r)
        k[((size_t)bm * N_ + nb + r) * D_ + (col0 - 64)] = __float2bfloat16(acc0[r]);
    }
    // V store (packed b64 along n; layout [c][n])
    alignas(8) __hip_bfloat16 tmp[4];
    #pragma unroll
    for (int r = 0; r < 4; ++r) tmp[r] = __float2bfloat16(acc1[r]);
    *reinterpret_cast<short4v*>(&vt[((size_t)bm * C_ + cV) * N_ + nb]) =
        *reinterpret_cast<const short4v*>(tmp);
  }
}

// ---------------------------------------------------------------------------
// Kernel 2: flash attention per (b,m), swapped-QK^T, fully in-register P
// (cvt_pk_bf16 + permlane32_swap), single-barrier double-buffered K/V
// pipeline. XCD-swizzled so all 8 q-tiles of one bm share an XCD's L2.
// Grid: 1024. Block 256 = 4 waves x 32 q-rows.
// ---------------------------------------------------------------------------
__global__ __launch_bounds__(256, 2) void attn_kernel(
    const float* __restrict__ x, const float* __restrict__ lam,
    const __hip_bfloat16* __restrict__ q, const __hip_bfloat16* __restrict__ k,
    const __hip_bfloat16* __restrict__ vt, float* __restrict__ out) {
  __shared__ alignas(16) __hip_bfloat16 kbuf[2][64 * 72];   // 9216 B each
  __shared__ alignas(16) __hip_bfloat16 vbuf[2][128 * 72];  // 18432 B each

  // XCD swizzle: hw assigns block h to XCD h%8; map so bm's 8 q-tiles
  // share xcd = bm%8.  h -> (xcd=h&7, s=h>>3) -> bm=(s>>3)*8+xcd, qt=s&7.
  int h   = blockIdx.x;
  int s_  = h >> 3;
  int bm  = (s_ >> 3) * 8 + (h & 7);
  int n0  = (s_ & 7) * 128;
  int b   = bm >> 5, m = bm & 31;
  int tid = threadIdx.x;
  int w = tid >> 6, l = tid & 63;
  int lq = l & 31, hi = l >> 5;

  const __hip_bfloat16* kbase = k + (size_t)bm * N_ * D_;
  const __hip_bfloat16* vbase = vt + (size_t)bm * C_ * N_;

  // staging chunk coords (16B chunks)
  int kr0 = tid >> 3,          kc0 = tid & 7;          // K chunks tid, tid+256
  int kr1 = (tid + 256) >> 3,  kc1 = tid & 7;
  int vr[4], vc = tid & 7;
  #pragma unroll
  for (int i = 0; i < 4; ++i) vr[i] = (tid + i * 256) >> 3;

  // Q fragments (B operand of S^T): lane = col q, k = d = 16*s + 8*hi + i
  short8 qf[4];
  {
    int n = n0 + w * 32 + lq;
    const __hip_bfloat16* qp = q + ((size_t)bm * N_ + n) * D_;
    #pragma unroll
    for (int s = 0; s < 4; ++s)
      qf[s] = *reinterpret_cast<const short8*>(qp + s * 16 + hi * 8);
  }

  f32x16 acc[4];
  const f32x16 z16 = {0.f,0.f,0.f,0.f,0.f,0.f,0.f,0.f,
                      0.f,0.f,0.f,0.f,0.f,0.f,0.f,0.f};
  #pragma unroll
  for (int ct = 0; ct < 4; ++ct) acc[ct] = z16;
  float m_run = -1e30f, l_run = 0.f;

  short8 kreg[2], vreg[4];
  // ---- prologue: stage tile 0 into buf 0 ----
  kreg[0] = *reinterpret_cast<const short8*>(&kbase[(size_t)kr0 * D_ + kc0 * 8]);
  kreg[1] = *reinterpret_cast<const short8*>(&kbase[(size_t)kr1 * D_ + kc1 * 8]);
  #pragma unroll
  for (int i = 0; i < 4; ++i)
    vreg[i] = *reinterpret_cast<const short8*>(&vbase[(size_t)vr[i] * N_ + vc * 8]);
  *reinterpret_cast<short8*>(&kbuf[0][kr0 * 72 + kc0 * 8]) = kreg[0];
  *reinterpret_cast<short8*>(&kbuf[0][kr1 * 72 + kc1 * 8]) = kreg[1];
  #pragma unroll
  for (int i = 0; i < 4; ++i)
    *reinterpret_cast<short8*>(&vbuf[0][vr[i] * 72 + vc * 8]) = vreg[i];
  __syncthreads();

  for (int t = 0; t < 16; ++t) {
    int cur = t & 1;
    // ---- issue next tile's global loads (latency hides under compute) ----
    if (t < 15) {
      int j0n = (t + 1) * 64;
      kreg[0] = *reinterpret_cast<const short8*>(&kbase[(size_t)(j0n + kr0) * D_ + kc0 * 8]);
      kreg[1] = *reinterpret_cast<const short8*>(&kbase[(size_t)(j0n + kr1) * D_ + kc1 * 8]);
      #pragma unroll
      for (int i = 0; i < 4; ++i)
        vreg[i] = *reinterpret_cast<const short8*>(&vbase[(size_t)vr[i] * N_ + j0n + vc * 8]);
    }

    const __hip_bfloat16* kt  = kbuf[cur];
    const __hip_bfloat16* vtt = vbuf[cur];

    // ---- S^T = K * Q^T : st[t32] holds kj rows (reg-local), q cols (lane)
    f32x16 st[2];
    st[0] = z16; st[1] = z16;
    #pragma unroll
    for (int s = 0; s < 4; ++s) {
      short8 kf0 = *reinterpret_cast<const short8*>(&kt[lq * 72 + s * 16 + hi * 8]);
      st[0] = __builtin_amdgcn_mfma_f32_32x32x16_bf16(kf0, qf[s], st[0], 0, 0, 0);
      short8 kf1 = *reinterpret_cast<const short8*>(&kt[(32 + lq) * 72 + s * 16 + hi * 8]);
      st[1] = __builtin_amdgcn_mfma_f32_32x32x16_bf16(kf1, qf[s], st[1], 0, 0, 0);
    }

    // ---- in-register online softmax (q = lq lane-local) ----
    float mx;
    {
      float t8[8];
      #pragma unroll
      for (int i = 0; i < 8; ++i)
        t8[i] = fmaxf(fmaxf(st[0][i], st[0][i + 8]), fmaxf(st[1][i], st[1][i + 8]));
      float a0 = fmaxf(fmaxf(t8[0], t8[1]), fmaxf(t8[2], t8[3]));
      float a1 = fmaxf(fmaxf(t8[4], t8[5]), fmaxf(t8[6], t8[7]));
      mx = fmaxf(a0, a1);
      mx = fmaxf(mx, __shfl_xor(mx, 32));
    }
    if (__any(mx > m_run + 8.0f)) {     // defer-max gate (exp2 domain, THR=8)
      float mnew = fmaxf(m_run, mx);
      float fac = EXP2(m_run - mnew);
      l_run *= fac;
      m_run = mnew;
      #pragma unroll
      for (int reg = 0; reg < 16; ++reg) {
        int qi = (reg & 3) + 8 * (reg >> 2) + 4 * hi;
        float f = __shfl(fac, qi);
        #pragma unroll
        for (int ct = 0; ct < 4; ++ct) acc[ct][reg] *= f;
      }
    }
    #pragma unroll
    for (int i = 0; i < 16; ++i) {
      st[0][i] = EXP2(st[0][i] - m_run);
      st[1][i] = EXP2(st[1][i] - m_run);
    }
    {
      float s8[8];
      #pragma unroll
      for (int i = 0; i < 8; ++i)
        s8[i] = (st[0][i] + st[0][i + 8]) + (st[1][i] + st[1][i + 8]);
      float rs = ((s8[0] + s8[1]) + (s8[2] + s8[3])) +
                 ((s8[4] + s8[5]) + (s8[6] + s8[7]));
      rs += __shfl_xor(rs, 32);
      l_run += rs;
    }

    // ---- build PV A-fragments fully in-register (cvt_pk + permlane) ----
    union W4 { int w[4]; short8 s8; } pf[4];
    #pragma unroll
    for (int t32 = 0; t32 < 2; ++t32) {
      int A = cvtpk_bf16(st[t32][0], st[t32][1]);
      int Bw = cvtpk_bf16(st[t32][2], st[t32][3]);
      int Cw = cvtpk_bf16(st[t32][4], st[t32][5]);
      int Dw = cvtpk_bf16(st[t32][6], st[t32][7]);
      plswap(A, Cw);
      plswap(Bw, Dw);
      pf[t32 * 2].w[0] = A;  pf[t32 * 2].w[1] = Bw;
      pf[t32 * 2].w[2] = Cw; pf[t32 * 2].w[3] = Dw;
      int E = cvtpk_bf16(st[t32][8], st[t32][9]);
      int F = cvtpk_bf16(st[t32][10], st[t32][11]);
      int G = cvtpk_bf16(st[t32][12], st[t32][13]);
      int H = cvtpk_bf16(st[t32][14], st[t32][15]);
      plswap(E, G);
      plswap(F, H);
      pf[t32 * 2 + 1].w[0] = E; pf[t32 * 2 + 1].w[1] = F;
      pf[t32 * 2 + 1].w[2] = G; pf[t32 * 2 + 1].w[3] = H;
    }

    // ---- O += P @ V ----
    #pragma unroll
    for (int kb = 0; kb < 4; ++kb) {
      #pragma unroll
      for (int ct = 0; ct < 4; ++ct) {
        short8 vf = *reinterpret_cast<const short8*>(
            &vtt[(ct * 32 + lq) * 72 + kb * 16 + hi * 8]);
        acc[ct] = __builtin_amdgcn_mfma_f32_32x32x16_bf16(pf[kb].s8, vf, acc[ct], 0, 0, 0);
      }
    }

    // ---- write staged regs into the other buffer, one barrier per tile ----
    if (t < 15) {
      int nxt = cur ^ 1;
      *reinterpret_cast<short8*>(&kbuf[nxt][kr0 * 72 + kc0 * 8]) = kreg[0];
      *reinterpret_cast<short8*>(&kbuf[nxt][kr1 * 72 + kc1 * 8]) = kreg[1];
      #pragma unroll
      for (int i = 0; i < 4; ++i)
        *reinterpret_cast<short8*>(&vbuf[nxt][vr[i] * 72 + vc * 8]) = vreg[i];
      __syncthreads();
    }
  }

  // ---- epilogue: out = x + (O / l) * lam ----
  float inv = 1.0f / l_run;        // lane's q = lq
  float rlv[16];
  #pragma unroll
  for (int reg = 0; reg < 16; ++reg) {
    int qi = (reg & 3) + 8 * (reg >> 2) + 4 * hi;
    rlv[reg] = __shfl(inv, qi);
  }
  #pragma unroll
  for (int ct = 0; ct < 4; ++ct) {
    int c = ct * 32 + lq;
    float lamc = lam[c];
    #pragma unroll
    for (int reg = 0; reg < 16; ++reg) {
      int qi = (reg & 3) + 8 * (reg >> 2) + 4 * hi;
      int n = n0 + w * 32 + qi;
      size_t idx = ((((size_t)b * N_ + n) * M_ + m) * C_) + c;
      out[idx] = x[idx] + acc[ct][reg] * rlv[reg] * lamc;
    }
  }
}

// ---------------------------------------------------------------------------
extern "C" void kernel_launch(void* const* d_in, const int* in_sizes, int n_in,
                              void* d_out, int out_size, void* d_ws, size_t ws_size,
                              hipStream_t stream) {
  const float* x     = (const float*)d_in[0];
  const float* gamma = (const float*)d_in[1];
  const float* beta  = (const float*)d_in[2];
  const float* wq    = (const float*)d_in[3];
  const float* wk    = (const float*)d_in[4];
  const float* wv    = (const float*)d_in[5];
  const float* lam   = (const float*)d_in[6];
  float* out = (float*)d_out;

  __hip_bfloat16* ws = (__hip_bfloat16*)d_ws;
  __hip_bfloat16* wt = ws;                        // 256*128
  __hip_bfloat16* q  = wt + 256 * 128;            // 128*1024*64
  __hip_bfloat16* k  = q + (size_t)BM_ * N_ * D_; // 128*1024*64
  __hip_bfloat16* vt = k + (size_t)BM_ * N_ * D_; // 128*128*1024 (transposed)

  prep_weights<<<128, 256, 0, stream>>>(wq, wk, wv, wt);
  ln_qkv<<<BM_ * (N_ / 128), 512, 0, stream>>>(x, gamma, beta, wt, q, k, vt);
  attn_kernel<<<BM_ * (N_ / 128), 256, 0, stream>>>(x, lam, q, k, vt, out);
}